// Round 12
// baseline (162.702 us; speedup 1.0000x reference)
//
#include <hip/hip_runtime.h>
#include <hip/hip_bf16.h>
#include <cstdint>
#include <cstddef>

// Problem constants (match reference)
#define N_EDGES_C 800000
#define N_NODES_C 50000
#define IN_CH_C   128
#define KDIM      256    // 2*IN_CH
#define HIDDEN_C  256

typedef __attribute__((ext_vector_type(8))) short sh8;
typedef __attribute__((ext_vector_type(4))) float f32x4;

__device__ __forceinline__ unsigned short f2bf(float f) {
  union { float f; unsigned u; } a; a.f = f;
  unsigned r = a.u + 0x7fffu + ((a.u >> 16) & 1u);  // RNE
  return (unsigned short)(r >> 16);
}

__device__ __forceinline__ void glds16(const unsigned short* g, void* l) {
  __builtin_amdgcn_global_load_lds(
      (const __attribute__((address_space(1))) unsigned int*)g,
      (__attribute__((address_space(3))) unsigned int*)l, 16, 0, 0);
}

// ============================ PRIMARY (TIER A) ============================
// zW[n][0:256] = z[n]@W1[0:128,:] + b1 ; zW[n][256:512] = z[n]@W1[128:256,:]
// logit(e) = sum_j relu(zW[row][j] + zW[col][256+j])*w2[j] + b2
// Edge pass: depth-3 data / depth-6 index software pipeline, inline-asm loads,
// counted vmcnt + sched_barrier fences (R11 proved the structure: 139->112).

// K1: W1 [256][256] f32 -> w1ct [512][128] bf16 (k-contiguous rows)
__global__ void cvt_w1ct_kernel(const float* __restrict__ w1,
                                unsigned short* __restrict__ w1ct) {
  const int k = blockIdx.x;     // 0..127
  const int j = threadIdx.x;    // 0..511
  const float v = (j < 256) ? w1[(size_t)k * 256 + j]
                            : w1[(size_t)(128 + k) * 256 + (j - 256)];
  w1ct[(size_t)j * 128 + k] = f2bf(v);
}

// K2: build zw [50000][512] bf16. 782 blocks x 512 thr (8 waves). (R8-proven.)
__global__ __launch_bounds__(512) void build_zw_kernel(
    const float* __restrict__ z,
    const unsigned short* __restrict__ w1ct,
    const float* __restrict__ b1,
    unsigned short* __restrict__ zw)
{
  __shared__ __align__(16) unsigned char Az[16384];
  const int tid = threadIdx.x;
  const int w   = tid >> 6;
  const int l   = tid & 63;
  const int l15 = l & 15;
  const int lg  = l >> 4;
  const int nb  = blockIdx.x;      // 0..781
  const int j0  = w * 64;

  {
    const int row = tid >> 3;
    const int fc  = (tid & 7) * 16;
    int node = nb * 64 + row;
    node = (node < N_NODES_C) ? node : (N_NODES_C - 1);
    const float4* zp = reinterpret_cast<const float4*>(
        z + (size_t)node * IN_CH_C + fc);
    float4 x0 = zp[0], x1 = zp[1], x2 = zp[2], x3 = zp[3];
    sh8 o0, o1;
    o0[0]=(short)f2bf(x0.x); o0[1]=(short)f2bf(x0.y); o0[2]=(short)f2bf(x0.z); o0[3]=(short)f2bf(x0.w);
    o0[4]=(short)f2bf(x1.x); o0[5]=(short)f2bf(x1.y); o0[6]=(short)f2bf(x1.z); o0[7]=(short)f2bf(x1.w);
    o1[0]=(short)f2bf(x2.x); o1[1]=(short)f2bf(x2.y); o1[2]=(short)f2bf(x2.z); o1[3]=(short)f2bf(x2.w);
    o1[4]=(short)f2bf(x3.x); o1[5]=(short)f2bf(x3.y); o1[6]=(short)f2bf(x3.z); o1[7]=(short)f2bf(x3.w);
    const int c0  = fc * 2;
    const int swz = (row & 7) << 4;
    *reinterpret_cast<sh8*>(Az + row * 256 + (c0 ^ swz))        = o0;
    *reinterpret_cast<sh8*>(Az + row * 256 + ((c0 + 16) ^ swz)) = o1;
  }

  sh8 bfr[4][4];
#pragma unroll
  for (int nt = 0; nt < 4; ++nt)
#pragma unroll
    for (int kk = 0; kk < 4; ++kk)
      bfr[nt][kk] = *reinterpret_cast<const sh8*>(
          w1ct + (size_t)(j0 + nt * 16 + l15) * 128 + kk * 32 + lg * 8);

  __syncthreads();

  const f32x4 fz = {0.f, 0.f, 0.f, 0.f};
  f32x4 acc[4][4];
#pragma unroll
  for (int mt = 0; mt < 4; ++mt)
#pragma unroll
    for (int nt = 0; nt < 4; ++nt)
      acc[mt][nt] = fz;

#pragma unroll
  for (int kk = 0; kk < 4; ++kk) {
#pragma unroll
    for (int mt = 0; mt < 4; ++mt) {
      const int row = mt * 16 + l15;
      const sh8 af = *reinterpret_cast<const sh8*>(
          Az + row * 256 + ((kk * 64 + lg * 16) ^ ((l15 & 7) << 4)));
#pragma unroll
      for (int nt = 0; nt < 4; ++nt)
        acc[mt][nt] = __builtin_amdgcn_mfma_f32_16x16x32_bf16(
            af, bfr[nt][kk], acc[mt][nt], 0, 0, 0);
    }
  }

#pragma unroll
  for (int nt = 0; nt < 4; ++nt) {
    const int j = j0 + nt * 16 + l15;
    const float bb = (j < 256) ? b1[j] : 0.f;
#pragma unroll
    for (int mt = 0; mt < 4; ++mt) {
#pragma unroll
      for (int r = 0; r < 4; ++r) {
        const int node = nb * 64 + mt * 16 + lg * 4 + r;
        if (node < N_NODES_C)
          zw[(size_t)node * 512 + j] = f2bf(acc[mt][nt][r] + bb);
      }
    }
  }
}

// ---- inline-asm load/wait primitives for the pipelined edge pass ----
#define GLDX4_0(dst, p)  asm volatile("global_load_dwordx4 %0, %1, off"            : "=v"(dst) : "v"(p))
#define GLDX4_16(dst, p) asm volatile("global_load_dwordx4 %0, %1, off offset:16"  : "=v"(dst) : "v"(p))
#define GLDW(dst, p)     asm volatile("global_load_dword %0, %1, off"              : "=v"(dst) : "v"(p))
#define VMWAIT(N)                                                          \
  asm volatile("s_waitcnt vmcnt(" #N ")" ::: "memory");                    \
  __builtin_amdgcn_sched_barrier(0);

#define UNPACK2(u, v, wa, wb)                                              \
  {                                                                        \
    float lo_ = __uint_as_float((u) << 16) + __uint_as_float((v) << 16);   \
    float hi_ = __uint_as_float((u) & 0xffff0000u) +                       \
                __uint_as_float((v) & 0xffff0000u);                        \
    a0 = fmaf(fmaxf(lo_, 0.f), (wa), a0);                                  \
    a1 = fmaf(fmaxf(hi_, 0.f), (wb), a1);                                  \
  }
#define STEP4(T, B, Wa, Wb)                                                \
  UNPACK2((T).x, (B).x, (Wa).x, (Wa).y)                                    \
  UNPACK2((T).y, (B).y, (Wa).z, (Wa).w)                                    \
  UNPACK2((T).z, (B).z, (Wb).x, (Wb).y)                                    \
  UNPACK2((T).w, (B).w, (Wb).z, (Wb).w)

// K3: pipelined edge pass v3. 3125 blocks x 256 thr; 16-lane group per edge;
// 16 sequential edges per group. Depth-3 data, depth-6 index; per-iteration
// vmcnt from exact oldest-first instruction bookkeeping (stores included):
// iter i contributes [store(i), I(i+6)x2, D(i+3)x4]; required at iter i are
// D(i) and I(i+3) (older than D(i)); younger-count => vmcnt value.
__global__ __launch_bounds__(256, 4) void edge_pass_pipe3(
    const unsigned short* __restrict__ zw,
    const int* __restrict__ ei,
    const float* __restrict__ w2,
    const float* __restrict__ b2,
    float* __restrict__ out)
{
  const int tid = threadIdx.x;
  const int q   = tid & 15;                        // 16-lane slice of an edge
  const int G   = (blockIdx.x * 256 + tid) >> 4;   // group id (50000 groups)
  const int e0  = G * 16;

  // hoisted: w2 slice (16 f32) + b2
  const float4* wp = reinterpret_cast<const float4*>(w2 + q * 16);
  const float4 W0 = wp[0], W1 = wp[1], W2r = wp[2], W3 = wp[3];
  const float b2v = b2[0];

  const char* zwB = (const char*)zw;
  const int   qo  = q * 32;                        // byte off in 512B half-row

  int rr[16], cc[16];
  rr[0] = ei[e0];     cc[0] = ei[N_EDGES_C + e0];
  rr[1] = ei[e0 + 1]; cc[1] = ei[N_EDGES_C + e0 + 1];
  rr[2] = ei[e0 + 2]; cc[2] = ei[N_EDGES_C + e0 + 2];
  // full drain so compiler-managed loads can't confuse the hand vmcnt counts
  asm volatile("s_waitcnt vmcnt(0)" ::: "memory");
  __builtin_amdgcn_sched_barrier(0);

  uint4 Tf[3][2], Bf[3][2];
  // prologue (emulates iters -3..-1): [I(3),D(0)] [I(4),D(1)] [I(5),D(2)]
  GLDW(rr[3], (const void*)(ei + e0 + 3));
  GLDW(cc[3], (const void*)(ei + N_EDGES_C + e0 + 3));
  {
    const char* ta = zwB + ((size_t)(unsigned)rr[0] << 10) + qo;
    const char* tb = zwB + ((size_t)(unsigned)cc[0] << 10) + 512 + qo;
    GLDX4_0(Tf[0][0], ta); GLDX4_16(Tf[0][1], ta);
    GLDX4_0(Bf[0][0], tb); GLDX4_16(Bf[0][1], tb);
  }
  GLDW(rr[4], (const void*)(ei + e0 + 4));
  GLDW(cc[4], (const void*)(ei + N_EDGES_C + e0 + 4));
  {
    const char* ta = zwB + ((size_t)(unsigned)rr[1] << 10) + qo;
    const char* tb = zwB + ((size_t)(unsigned)cc[1] << 10) + 512 + qo;
    GLDX4_0(Tf[1][0], ta); GLDX4_16(Tf[1][1], ta);
    GLDX4_0(Bf[1][0], tb); GLDX4_16(Bf[1][1], tb);
  }
  GLDW(rr[5], (const void*)(ei + e0 + 5));
  GLDW(cc[5], (const void*)(ei + N_EDGES_C + e0 + 5));
  {
    const char* ta = zwB + ((size_t)(unsigned)rr[2] << 10) + qo;
    const char* tb = zwB + ((size_t)(unsigned)cc[2] << 10) + 512 + qo;
    GLDX4_0(Tf[2][0], ta); GLDX4_16(Tf[2][1], ta);
    GLDX4_0(Bf[2][0], tb); GLDX4_16(Bf[2][1], tb);
  }

#pragma unroll
  for (int i = 0; i < 16; ++i) {
    const int s = i % 3;
    // exact younger-counts (see header comment); under-drain impossible
    if (i == 0)       { VMWAIT(12) }
    else if (i == 1)  { VMWAIT(13) }
    else if (i <= 10) { VMWAIT(14) }
    else if (i == 11) { VMWAIT(12) }
    else if (i <= 13) { VMWAIT(10) }
    else if (i == 14) { VMWAIT(6) }
    else              { VMWAIT(2) }

    // compute edge e0+i from set s
    float a0 = 0.f, a1 = 0.f;
    STEP4(Tf[s][0], Bf[s][0], W0, W1)
    STEP4(Tf[s][1], Bf[s][1], W2r, W3)
    float v = a0 + a1;
    v += __shfl_xor(v, 1, 64);
    v += __shfl_xor(v, 2, 64);
    v += __shfl_xor(v, 4, 64);
    v += __shfl_xor(v, 8, 64);
    if (q == 0)
      out[e0 + i] = 1.f / (1.f + __expf(-(v + b2v)));

    // issue I(i+6)
    if (i <= 9) {
      GLDW(rr[i + 6], (const void*)(ei + e0 + i + 6));
      GLDW(cc[i + 6], (const void*)(ei + N_EDGES_C + e0 + i + 6));
    }
    // issue D(i+3) into set s (regs free: edge i consumed)
    if (i <= 12) {
      const char* ta = zwB + ((size_t)(unsigned)rr[i + 3] << 10) + qo;
      const char* tb = zwB + ((size_t)(unsigned)cc[i + 3] << 10) + 512 + qo;
      GLDX4_0(Tf[s][0], ta); GLDX4_16(Tf[s][1], ta);
      GLDX4_0(Bf[s][0], tb); GLDX4_16(Bf[s][1], tb);
    }
  }
  asm volatile("s_waitcnt vmcnt(0)" ::: "memory");
}

// ============================ MIDDLE PATH (R5) ============================
#define TM        32
#define NBLK      512
#define THREADS   512

__global__ void cvt_z_kernel(const float* __restrict__ z,
                             unsigned short* __restrict__ zb) {
  int i = blockIdx.x * blockDim.x + threadIdx.x;
  float4 v = reinterpret_cast<const float4*>(z)[i];
  ushort4 o;
  o.x = f2bf(v.x); o.y = f2bf(v.y); o.z = f2bf(v.z); o.w = f2bf(v.w);
  reinterpret_cast<ushort4*>(zb)[i] = o;
}

__global__ void cvt_w1t_kernel(const float* __restrict__ w1,
                               unsigned short* __restrict__ w1t) {
  int k = blockIdx.x;
  int n = threadIdx.x;
  w1t[(size_t)n * KDIM + k] = f2bf(w1[(size_t)k * HIDDEN_C + n]);
}

__global__ __launch_bounds__(THREADS, 4) void decoder_persist(
    const unsigned short* __restrict__ zb,
    const int* __restrict__ ei,
    const unsigned short* __restrict__ w1t,
    const float* __restrict__ b1,
    const float* __restrict__ w2,
    const float* __restrict__ b2,
    float* __restrict__ out)
{
  __shared__ __align__(16) unsigned char lds[3 * 16384 + 2048];
  float* red = (float*)(lds + 3 * 16384);

  const int tid = threadIdx.x;
  const int w   = tid >> 6;
  const int l   = tid & 63;
  const int l15 = l & 15;
  const int lg  = l >> 4;
  const int n0  = w * 32;

  const int b    = blockIdx.x;
  const bool big = (b < 424);
  const int ntb  = big ? 49 : 48;
  const int S    = big ? (49 * b) : (49 * 424 + 48 * (b - 424));
  const int tb   = S * TM;

  const int nd   = (l >> 4) & 1;
  const int eo0  = 4 * w + (l >> 5);
  const int eo1  = eo0 + 2;
  const int sc   = (l & 31) * 16;
  const int off0 = (sc ^ ((eo0 & 7) << 4)) & 255;
  const int off1 = (sc ^ ((eo1 & 7) << 4)) & 255;
  const int* eip0 = ei + (size_t)nd * N_EDGES_C + tb + eo0;
  const int* eip1 = ei + (size_t)nd * N_EDGES_C + tb + eo1;

  sh8 bfr[2][8];
#pragma unroll
  for (int nt = 0; nt < 2; ++nt)
#pragma unroll
    for (int kk = 0; kk < 8; ++kk)
      bfr[nt][kk] = *reinterpret_cast<const sh8*>(
          w1t + (size_t)(n0 + nt * 16 + l15) * KDIM + kk * 32 + lg * 8);

  const float b1v0 = b1[n0 + l15],      b1v1 = b1[n0 + 16 + l15];
  const float w2v0 = w2[n0 + l15],      w2v1 = w2[n0 + 16 + l15];
  const float b2v  = b2[0];

  const int b2b = (l15 >> 2) & 1;
  const int Eb  = l15 * 512 + 64 * b2b + ((lg * 16) ^ ((l15 & 3) << 4));
  const int Ob  = Eb - 128 * b2b;

  int ia0 = eip0[0],      ia1 = eip1[0];
  __builtin_amdgcn_sched_barrier(0);
  int ib0 = eip0[TM],     ib1 = eip1[TM];
  __builtin_amdgcn_sched_barrier(0);
  glds16(zb + (size_t)ia0 * IN_CH_C + (off0 >> 1), lds + 0 * 16384 + (2 * w + 0) * 1024);
  glds16(zb + (size_t)ia1 * IN_CH_C + (off1 >> 1), lds + 0 * 16384 + (2 * w + 1) * 1024);
  __builtin_amdgcn_sched_barrier(0);
  int jc0 = eip0[2 * TM], jc1 = eip1[2 * TM];
  __builtin_amdgcn_sched_barrier(0);
  glds16(zb + (size_t)ib0 * IN_CH_C + (off0 >> 1), lds + 1 * 16384 + (2 * w + 0) * 1024);
  glds16(zb + (size_t)ib1 * IN_CH_C + (off1 >> 1), lds + 1 * 16384 + (2 * w + 1) * 1024);
  __builtin_amdgcn_sched_barrier(0);

  int cur = 0, nx1 = 16384, nx2 = 32768;

#pragma unroll 1
  for (int t = 0; t < ntb; ++t) {
    __builtin_amdgcn_sched_barrier(0);
    asm volatile("s_waitcnt vmcnt(4) lgkmcnt(0)" ::: "memory");
    __builtin_amdgcn_s_barrier();
    __builtin_amdgcn_sched_barrier(0);

    const int tn = (t + 3 < ntb) ? (t + 3) : (ntb - 1);
    int ni0 = eip0[tn * TM];
    int ni1 = eip1[tn * TM];
    __builtin_amdgcn_sched_barrier(0);

    glds16(zb + (size_t)jc0 * IN_CH_C + (off0 >> 1), lds + nx2 + (2 * w + 0) * 1024);
    glds16(zb + (size_t)jc1 * IN_CH_C + (off1 >> 1), lds + nx2 + (2 * w + 1) * 1024);
    __builtin_amdgcn_sched_barrier(0);

    const f32x4 fz = {0.f, 0.f, 0.f, 0.f};
    f32x4 acc[2][2] = {{fz, fz}, {fz, fz}};
    __builtin_amdgcn_s_setprio(1);
#pragma unroll
    for (int kk = 0; kk < 8; ++kk) {
      const int kb_ = ((kk & 1) ? Ob : Eb) + kk * 64;
#pragma unroll
      for (int mt = 0; mt < 2; ++mt) {
        const sh8 af = *reinterpret_cast<const sh8*>(lds + cur + kb_ + mt * 8192);
        acc[mt][0] = __builtin_amdgcn_mfma_f32_16x16x32_bf16(af, bfr[0][kk], acc[mt][0], 0, 0, 0);
        acc[mt][1] = __builtin_amdgcn_mfma_f32_16x16x32_bf16(af, bfr[1][kk], acc[mt][1], 0, 0, 0);
      }
    }
    __builtin_amdgcn_s_setprio(0);

    float pl[2][4];
#pragma unroll
    for (int mt = 0; mt < 2; ++mt)
#pragma unroll
      for (int r = 0; r < 4; ++r) {
        float v0 = fmaxf(acc[mt][0][r] + b1v0, 0.f);
        float v1 = fmaxf(acc[mt][1][r] + b1v1, 0.f);
        pl[mt][r] = v0 * w2v0 + v1 * w2v1;
      }
#pragma unroll
    for (int s = 1; s < 16; s <<= 1)
#pragma unroll
      for (int mt = 0; mt < 2; ++mt)
#pragma unroll
        for (int r = 0; r < 4; ++r)
          pl[mt][r] += __shfl_xor(pl[mt][r], s, 64);
    if (l15 == 0) {
#pragma unroll
      for (int mt = 0; mt < 2; ++mt) {
        float4 v = make_float4(pl[mt][0], pl[mt][1], pl[mt][2], pl[mt][3]);
        *reinterpret_cast<float4*>(&red[(t & 1) * 256 + w * 32 + mt * 16 + lg * 4]) = v;
      }
    }

    if (t > 0 && tid < TM) {
      float s = b2v;
#pragma unroll
      for (int ww = 0; ww < 8; ++ww)
        s += red[((t - 1) & 1) * 256 + ww * 32 + tid];
      out[tb + (t - 1) * TM + tid] = 1.f / (1.f + __expf(-s));
    }

    jc0 = ni0; jc1 = ni1;
    int tmp = cur; cur = nx1; nx1 = nx2; nx2 = tmp;
  }

  __builtin_amdgcn_sched_barrier(0);
  asm volatile("s_waitcnt lgkmcnt(0)" ::: "memory");
  __builtin_amdgcn_s_barrier();
  __builtin_amdgcn_sched_barrier(0);
  if (tid < TM) {
    float s = b2v;
#pragma unroll
    for (int ww = 0; ww < 8; ++ww)
      s += red[((ntb - 1) & 1) * 256 + ww * 32 + tid];
    out[tb + (ntb - 1) * TM + tid] = 1.f / (1.f + __expf(-s));
  }
  asm volatile("s_waitcnt vmcnt(0)" ::: "memory");
}

// ============================ FALLBACK PATH ============================
#define BM 64
__global__ __launch_bounds__(512, 6) void decoder_fb(
    const float* __restrict__ z, const int* __restrict__ ei,
    const unsigned short* __restrict__ w1t, const float* __restrict__ b1,
    const float* __restrict__ w2, const float* __restrict__ b2,
    float* __restrict__ out)
{
  __shared__ __align__(16) unsigned char lds[BM * 512];
  const int tid = threadIdx.x, wave = tid >> 6, lane = tid & 63;
  const int l15 = lane & 15, lg = lane >> 4, base = blockIdx.x * BM;
  {
    const int e = tid & 63, w8 = tid >> 6, nd = w8 >> 2;
    const int idx = ei[nd * N_EDGES_C + base + e];
    const int swzw = (e & 7) << 4;
    char* dstrow = (char*)lds + e * 512;
    const float* src = z + (size_t)idx * IN_CH_C + (w8 & 3) * 32;
    float4 tf[8];
#pragma unroll
    for (int i = 0; i < 8; ++i) tf[i] = reinterpret_cast<const float4*>(src)[i];
#pragma unroll
    for (int i = 0; i < 4; ++i) {
      sh8 o; const float4 x0 = tf[2*i], x1 = tf[2*i+1];
      o[0]=(short)f2bf(x0.x); o[1]=(short)f2bf(x0.y); o[2]=(short)f2bf(x0.z); o[3]=(short)f2bf(x0.w);
      o[4]=(short)f2bf(x1.x); o[5]=(short)f2bf(x1.y); o[6]=(short)f2bf(x1.z); o[7]=(short)f2bf(x1.w);
      *reinterpret_cast<sh8*>(dstrow + ((w8 * 64 + i * 16) ^ swzw)) = o;
    }
  }
  __syncthreads();
  const int n0 = wave * 32;
  const int swz = (l15 & 7) << 4;
  const int Ebase = l15 * 512 + ((lg * 16) ^ swz);
  const int Obase = Ebase - ((swz & 64) << 1);
  const f32x4 fz = {0.f,0.f,0.f,0.f};
  f32x4 acc[4][2];
#pragma unroll
  for (int mt = 0; mt < 4; ++mt) { acc[mt][0] = fz; acc[mt][1] = fz; }
#pragma unroll
  for (int kk = 0; kk < 8; ++kk) {
    const int kOff = kk * 32 + lg * 8;
    sh8 bfrag[2];
#pragma unroll
    for (int nt = 0; nt < 2; ++nt)
      bfrag[nt] = *reinterpret_cast<const sh8*>(w1t + (size_t)(n0 + nt*16 + l15) * KDIM + kOff);
    const int kbase = ((kk & 1) ? Obase : Ebase) + kk * 64;
#pragma unroll
    for (int mt = 0; mt < 4; ++mt) {
      const sh8 af = *reinterpret_cast<const sh8*>((char*)lds + (kbase + mt * 8192));
      acc[mt][0] = __builtin_amdgcn_mfma_f32_16x16x32_bf16(af, bfrag[0], acc[mt][0], 0, 0, 0);
      acc[mt][1] = __builtin_amdgcn_mfma_f32_16x16x32_bf16(af, bfrag[1], acc[mt][1], 0, 0, 0);
    }
  }
  float plog[4][4];
#pragma unroll
  for (int mt = 0; mt < 4; ++mt)
#pragma unroll
    for (int r = 0; r < 4; ++r) plog[mt][r] = 0.f;
#pragma unroll
  for (int nt = 0; nt < 2; ++nt) {
    const int j = n0 + nt * 16 + l15;
    const float b1v = b1[j], w2v = w2[j];
#pragma unroll
    for (int mt = 0; mt < 4; ++mt)
#pragma unroll
      for (int r = 0; r < 4; ++r)
        plog[mt][r] = fmaf(fmaxf(acc[mt][nt][r] + b1v, 0.f), w2v, plog[mt][r]);
  }
#pragma unroll
  for (int s = 1; s < 16; s <<= 1)
#pragma unroll
    for (int mt = 0; mt < 4; ++mt)
#pragma unroll
      for (int r = 0; r < 4; ++r)
        plog[mt][r] += __shfl_xor(plog[mt][r], s, 64);
  __syncthreads();
  float* red = (float*)lds;
  if (l15 == 0)
#pragma unroll
    for (int mt = 0; mt < 4; ++mt)
#pragma unroll
      for (int r = 0; r < 4; ++r)
        red[wave * 64 + mt * 16 + lg * 4 + r] = plog[mt][r];
  __syncthreads();
  if (tid < BM) {
    float s = b2[0];
#pragma unroll
    for (int w = 0; w < 8; ++w) s += red[w * 64 + tid];
    out[base + tid] = 1.f / (1.f + __expf(-s));
  }
}

extern "C" void kernel_launch(void* const* d_in, const int* in_sizes, int n_in,
                              void* d_out, int out_size, void* d_ws, size_t ws_size,
                              hipStream_t stream) {
  const float* z  = (const float*)d_in[0];
  const int*   ei = (const int*)d_in[1];
  const float* W1 = (const float*)d_in[2];
  const float* b1 = (const float*)d_in[3];
  const float* W2 = (const float*)d_in[4];
  const float* b2 = (const float*)d_in[5];
  float* out = (float*)d_out;

  const size_t o_w1   = 0;                                   // 128 KB
  const size_t o_zw   = 131072;
  const size_t need_A = o_zw + (size_t)N_NODES_C * 512 * 2;  // 51,331,072
  const size_t need_mid = 131072 + (size_t)N_NODES_C * IN_CH_C * 2; // 12,931,072

  if (ws_size >= need_A) {
    unsigned short* w1ct = (unsigned short*)((char*)d_ws + o_w1);
    unsigned short* zw   = (unsigned short*)((char*)d_ws + o_zw);
    cvt_w1ct_kernel<<<128, 512, 0, stream>>>(W1, w1ct);
    build_zw_kernel<<<(N_NODES_C + 63) / 64, 512, 0, stream>>>(z, w1ct, b1, zw);
    edge_pass_pipe3<<<3125, 256, 0, stream>>>(zw, ei, W2, b2, out);
  } else if (ws_size >= need_mid) {
    unsigned short* w1t = (unsigned short*)d_ws;
    unsigned short* zb  = (unsigned short*)((char*)d_ws + 131072);
    cvt_w1t_kernel<<<KDIM, HIDDEN_C, 0, stream>>>(W1, w1t);
    cvt_z_kernel<<<(N_NODES_C * IN_CH_C / 4) / 256, 256, 0, stream>>>(z, zb);
    decoder_persist<<<NBLK, THREADS, 0, stream>>>(zb, ei, w1t, b1, W2, b2, out);
  } else {
    unsigned short* w1t = (unsigned short*)d_ws;
    cvt_w1t_kernel<<<KDIM, HIDDEN_C, 0, stream>>>(W1, w1t);
    decoder_fb<<<N_EDGES_C / BM, 512, 0, stream>>>(z, ei, w1t, b1, W2, b2, out);
  }
}

// Round 13
// 160.641 us; speedup vs baseline: 1.0128x; 1.0128x over previous
//
#include <hip/hip_runtime.h>
#include <hip/hip_bf16.h>
#include <cstdint>
#include <cstddef>

// Problem constants (match reference)
#define N_EDGES_C 800000
#define N_NODES_C 50000
#define IN_CH_C   128
#define KDIM      256    // 2*IN_CH
#define HIDDEN_C  256

typedef __attribute__((ext_vector_type(8))) short sh8;
typedef __attribute__((ext_vector_type(4))) float f32x4;

__device__ __forceinline__ unsigned short f2bf(float f) {
  union { float f; unsigned u; } a; a.f = f;
  unsigned r = a.u + 0x7fffu + ((a.u >> 16) & 1u);  // RNE
  return (unsigned short)(r >> 16);
}

__device__ __forceinline__ void glds16(const unsigned short* g, void* l) {
  __builtin_amdgcn_global_load_lds(
      (const __attribute__((address_space(1))) unsigned int*)g,
      (__attribute__((address_space(3))) unsigned int*)l, 16, 0, 0);
}

// ============================ PRIMARY (TIER A) ============================
// zW[n][0:256] = z[n]@W1[0:128,:] + b1 ; zW[n][256:512] = z[n]@W1[128:256,:]
// logit(e) = sum_j relu(zW[row][j] + zW[col][256+j])*w2[j] + b2
// Pass: depth-3/depth-6 inline-asm pipeline (R11/R12: 3.5 TB/s fetch wall).
// Build: swapped-operand MFMA (C[j][node]) so each lane packs 4 consecutive
// j into 8B stores — 16x dwordx2/thread vs 128x 2B scatter (R12 post-mortem).

// K1: W1 [256][256] f32 -> w1ct [512][128] bf16 (k-contiguous rows)
__global__ void cvt_w1ct_kernel(const float* __restrict__ w1,
                                unsigned short* __restrict__ w1ct) {
  const int k = blockIdx.x;     // 0..127
  const int j = threadIdx.x;    // 0..511
  const float v = (j < 256) ? w1[(size_t)k * 256 + j]
                            : w1[(size_t)(128 + k) * 256 + (j - 256)];
  w1ct[(size_t)j * 128 + k] = f2bf(v);
}

// K2: build zw [50000][512] bf16. 782 blocks x 512 thr (8 waves).
// Wave w owns j-range [w*64, w*64+64). A = w1ct (M=j), B = z-tile (N=node).
// C layout: col=node (l&15), row=j (lg*4+r) -> lane holds 4 consecutive j
// for one node -> packed uint2 stores.
__global__ __launch_bounds__(512) void build_zw_kernel(
    const float* __restrict__ z,
    const unsigned short* __restrict__ w1ct,
    const float* __restrict__ b1,
    unsigned short* __restrict__ zw)
{
  __shared__ __align__(16) unsigned char Az[16384];
  const int tid = threadIdx.x;
  const int w   = tid >> 6;
  const int l   = tid & 63;
  const int l15 = l & 15;
  const int lg  = l >> 4;
  const int nb  = blockIdx.x;      // 0..781
  const int j0  = w * 64;

  // ---- reg-staged z-tile: 64 nodes x 128 k bf16, XOR swizzle (R8-proven) ----
  {
    const int row = tid >> 3;
    const int fc  = (tid & 7) * 16;
    int node = nb * 64 + row;
    node = (node < N_NODES_C) ? node : (N_NODES_C - 1);
    const float4* zp = reinterpret_cast<const float4*>(
        z + (size_t)node * IN_CH_C + fc);
    float4 x0 = zp[0], x1 = zp[1], x2 = zp[2], x3 = zp[3];
    sh8 o0, o1;
    o0[0]=(short)f2bf(x0.x); o0[1]=(short)f2bf(x0.y); o0[2]=(short)f2bf(x0.z); o0[3]=(short)f2bf(x0.w);
    o0[4]=(short)f2bf(x1.x); o0[5]=(short)f2bf(x1.y); o0[6]=(short)f2bf(x1.z); o0[7]=(short)f2bf(x1.w);
    o1[0]=(short)f2bf(x2.x); o1[1]=(short)f2bf(x2.y); o1[2]=(short)f2bf(x2.z); o1[3]=(short)f2bf(x2.w);
    o1[4]=(short)f2bf(x3.x); o1[5]=(short)f2bf(x3.y); o1[6]=(short)f2bf(x3.z); o1[7]=(short)f2bf(x3.w);
    const int c0  = fc * 2;
    const int swz = (row & 7) << 4;
    *reinterpret_cast<sh8*>(Az + row * 256 + (c0 ^ swz))        = o0;
    *reinterpret_cast<sh8*>(Az + row * 256 + ((c0 + 16) ^ swz)) = o1;
  }

  // A preload: w1ct fragments [jt][kk] (row j = j0+jt*16+l15, k-contiguous)
  sh8 afr[4][4];
#pragma unroll
  for (int jt = 0; jt < 4; ++jt)
#pragma unroll
    for (int kk = 0; kk < 4; ++kk)
      afr[jt][kk] = *reinterpret_cast<const sh8*>(
          w1ct + (size_t)(j0 + jt * 16 + l15) * 128 + kk * 32 + lg * 8);

  __syncthreads();

  const f32x4 fz = {0.f, 0.f, 0.f, 0.f};
  f32x4 acc[4][4];   // [jt][nt]
#pragma unroll
  for (int jt = 0; jt < 4; ++jt)
#pragma unroll
    for (int nt = 0; nt < 4; ++nt)
      acc[jt][nt] = fz;

#pragma unroll
  for (int kk = 0; kk < 4; ++kk) {
#pragma unroll
    for (int nt = 0; nt < 4; ++nt) {
      const int nrow = nt * 16 + l15;   // node within tile (B col = l15)
      const sh8 bf = *reinterpret_cast<const sh8*>(
          Az + nrow * 256 + ((kk * 64 + lg * 16) ^ ((l15 & 7) << 4)));
#pragma unroll
      for (int jt = 0; jt < 4; ++jt)
        acc[jt][nt] = __builtin_amdgcn_mfma_f32_16x16x32_bf16(
            afr[jt][kk], bf, acc[jt][nt], 0, 0, 0);
    }
  }

  // C write: node = nb*64 + nt*16 + l15, j = j0 + jt*16 + lg*4 + r (r=0..3)
  // 4 consecutive j per lane -> 2 packed dwords -> uint2 store (8B aligned).
#pragma unroll
  for (int jt = 0; jt < 4; ++jt) {
    const int jbase = j0 + jt * 16 + lg * 4;
    float4 bb = make_float4(0.f, 0.f, 0.f, 0.f);
    if (w < 4) bb = *reinterpret_cast<const float4*>(b1 + jbase);
#pragma unroll
    for (int nt = 0; nt < 4; ++nt) {
      const int node = nb * 64 + nt * 16 + l15;
      if (node < N_NODES_C) {
        const unsigned lo = (unsigned)f2bf(acc[jt][nt][0] + bb.x)
                          | ((unsigned)f2bf(acc[jt][nt][1] + bb.y) << 16);
        const unsigned hi = (unsigned)f2bf(acc[jt][nt][2] + bb.z)
                          | ((unsigned)f2bf(acc[jt][nt][3] + bb.w) << 16);
        uint2 v; v.x = lo; v.y = hi;
        *reinterpret_cast<uint2*>(zw + (size_t)node * 512 + jbase) = v;
      }
    }
  }
}

// ---- inline-asm load/wait primitives for the pipelined edge pass ----
#define GLDX4_0(dst, p)  asm volatile("global_load_dwordx4 %0, %1, off"            : "=v"(dst) : "v"(p))
#define GLDX4_16(dst, p) asm volatile("global_load_dwordx4 %0, %1, off offset:16"  : "=v"(dst) : "v"(p))
#define GLDW(dst, p)     asm volatile("global_load_dword %0, %1, off"              : "=v"(dst) : "v"(p))
#define VMWAIT(N)                                                          \
  asm volatile("s_waitcnt vmcnt(" #N ")" ::: "memory");                    \
  __builtin_amdgcn_sched_barrier(0);

#define UNPACK2(u, v, wa, wb)                                              \
  {                                                                        \
    float lo_ = __uint_as_float((u) << 16) + __uint_as_float((v) << 16);   \
    float hi_ = __uint_as_float((u) & 0xffff0000u) +                       \
                __uint_as_float((v) & 0xffff0000u);                        \
    a0 = fmaf(fmaxf(lo_, 0.f), (wa), a0);                                  \
    a1 = fmaf(fmaxf(hi_, 0.f), (wb), a1);                                  \
  }
#define STEP4(T, B, Wa, Wb)                                                \
  UNPACK2((T).x, (B).x, (Wa).x, (Wa).y)                                    \
  UNPACK2((T).y, (B).y, (Wa).z, (Wa).w)                                    \
  UNPACK2((T).z, (B).z, (Wb).x, (Wb).y)                                    \
  UNPACK2((T).w, (B).w, (Wb).z, (Wb).w)

// K3: pipelined edge pass v3 (R12; at the 3.5 TB/s fetch wall).
__global__ __launch_bounds__(256, 4) void edge_pass_pipe3(
    const unsigned short* __restrict__ zw,
    const int* __restrict__ ei,
    const float* __restrict__ w2,
    const float* __restrict__ b2,
    float* __restrict__ out)
{
  const int tid = threadIdx.x;
  const int q   = tid & 15;                        // 16-lane slice of an edge
  const int G   = (blockIdx.x * 256 + tid) >> 4;   // group id (50000 groups)
  const int e0  = G * 16;

  const float4* wp = reinterpret_cast<const float4*>(w2 + q * 16);
  const float4 W0 = wp[0], W1 = wp[1], W2r = wp[2], W3 = wp[3];
  const float b2v = b2[0];

  const char* zwB = (const char*)zw;
  const int   qo  = q * 32;

  int rr[16], cc[16];
  rr[0] = ei[e0];     cc[0] = ei[N_EDGES_C + e0];
  rr[1] = ei[e0 + 1]; cc[1] = ei[N_EDGES_C + e0 + 1];
  rr[2] = ei[e0 + 2]; cc[2] = ei[N_EDGES_C + e0 + 2];
  asm volatile("s_waitcnt vmcnt(0)" ::: "memory");
  __builtin_amdgcn_sched_barrier(0);

  uint4 Tf[3][2], Bf[3][2];
  GLDW(rr[3], (const void*)(ei + e0 + 3));
  GLDW(cc[3], (const void*)(ei + N_EDGES_C + e0 + 3));
  {
    const char* ta = zwB + ((size_t)(unsigned)rr[0] << 10) + qo;
    const char* tb = zwB + ((size_t)(unsigned)cc[0] << 10) + 512 + qo;
    GLDX4_0(Tf[0][0], ta); GLDX4_16(Tf[0][1], ta);
    GLDX4_0(Bf[0][0], tb); GLDX4_16(Bf[0][1], tb);
  }
  GLDW(rr[4], (const void*)(ei + e0 + 4));
  GLDW(cc[4], (const void*)(ei + N_EDGES_C + e0 + 4));
  {
    const char* ta = zwB + ((size_t)(unsigned)rr[1] << 10) + qo;
    const char* tb = zwB + ((size_t)(unsigned)cc[1] << 10) + 512 + qo;
    GLDX4_0(Tf[1][0], ta); GLDX4_16(Tf[1][1], ta);
    GLDX4_0(Bf[1][0], tb); GLDX4_16(Bf[1][1], tb);
  }
  GLDW(rr[5], (const void*)(ei + e0 + 5));
  GLDW(cc[5], (const void*)(ei + N_EDGES_C + e0 + 5));
  {
    const char* ta = zwB + ((size_t)(unsigned)rr[2] << 10) + qo;
    const char* tb = zwB + ((size_t)(unsigned)cc[2] << 10) + 512 + qo;
    GLDX4_0(Tf[2][0], ta); GLDX4_16(Tf[2][1], ta);
    GLDX4_0(Bf[2][0], tb); GLDX4_16(Bf[2][1], tb);
  }

#pragma unroll
  for (int i = 0; i < 16; ++i) {
    const int s = i % 3;
    if (i == 0)       { VMWAIT(12) }
    else if (i == 1)  { VMWAIT(13) }
    else if (i <= 10) { VMWAIT(14) }
    else if (i == 11) { VMWAIT(12) }
    else if (i <= 13) { VMWAIT(10) }
    else if (i == 14) { VMWAIT(6) }
    else              { VMWAIT(2) }

    float a0 = 0.f, a1 = 0.f;
    STEP4(Tf[s][0], Bf[s][0], W0, W1)
    STEP4(Tf[s][1], Bf[s][1], W2r, W3)
    float v = a0 + a1;
    v += __shfl_xor(v, 1, 64);
    v += __shfl_xor(v, 2, 64);
    v += __shfl_xor(v, 4, 64);
    v += __shfl_xor(v, 8, 64);
    if (q == 0)
      out[e0 + i] = 1.f / (1.f + __expf(-(v + b2v)));

    if (i <= 9) {
      GLDW(rr[i + 6], (const void*)(ei + e0 + i + 6));
      GLDW(cc[i + 6], (const void*)(ei + N_EDGES_C + e0 + i + 6));
    }
    if (i <= 12) {
      const char* ta = zwB + ((size_t)(unsigned)rr[i + 3] << 10) + qo;
      const char* tb = zwB + ((size_t)(unsigned)cc[i + 3] << 10) + 512 + qo;
      GLDX4_0(Tf[s][0], ta); GLDX4_16(Tf[s][1], ta);
      GLDX4_0(Bf[s][0], tb); GLDX4_16(Bf[s][1], tb);
    }
  }
  asm volatile("s_waitcnt vmcnt(0)" ::: "memory");
}

// ============================ MIDDLE PATH (R5) ============================
#define TM        32
#define NBLK      512
#define THREADS   512

__global__ void cvt_z_kernel(const float* __restrict__ z,
                             unsigned short* __restrict__ zb) {
  int i = blockIdx.x * blockDim.x + threadIdx.x;
  float4 v = reinterpret_cast<const float4*>(z)[i];
  ushort4 o;
  o.x = f2bf(v.x); o.y = f2bf(v.y); o.z = f2bf(v.z); o.w = f2bf(v.w);
  reinterpret_cast<ushort4*>(zb)[i] = o;
}

__global__ void cvt_w1t_kernel(const float* __restrict__ w1,
                               unsigned short* __restrict__ w1t) {
  int k = blockIdx.x;
  int n = threadIdx.x;
  w1t[(size_t)n * KDIM + k] = f2bf(w1[(size_t)k * HIDDEN_C + n]);
}

__global__ __launch_bounds__(THREADS, 4) void decoder_persist(
    const unsigned short* __restrict__ zb,
    const int* __restrict__ ei,
    const unsigned short* __restrict__ w1t,
    const float* __restrict__ b1,
    const float* __restrict__ w2,
    const float* __restrict__ b2,
    float* __restrict__ out)
{
  __shared__ __align__(16) unsigned char lds[3 * 16384 + 2048];
  float* red = (float*)(lds + 3 * 16384);

  const int tid = threadIdx.x;
  const int w   = tid >> 6;
  const int l   = tid & 63;
  const int l15 = l & 15;
  const int lg  = l >> 4;
  const int n0  = w * 32;

  const int b    = blockIdx.x;
  const bool big = (b < 424);
  const int ntb  = big ? 49 : 48;
  const int S    = big ? (49 * b) : (49 * 424 + 48 * (b - 424));
  const int tb   = S * TM;

  const int nd   = (l >> 4) & 1;
  const int eo0  = 4 * w + (l >> 5);
  const int eo1  = eo0 + 2;
  const int sc   = (l & 31) * 16;
  const int off0 = (sc ^ ((eo0 & 7) << 4)) & 255;
  const int off1 = (sc ^ ((eo1 & 7) << 4)) & 255;
  const int* eip0 = ei + (size_t)nd * N_EDGES_C + tb + eo0;
  const int* eip1 = ei + (size_t)nd * N_EDGES_C + tb + eo1;

  sh8 bfr[2][8];
#pragma unroll
  for (int nt = 0; nt < 2; ++nt)
#pragma unroll
    for (int kk = 0; kk < 8; ++kk)
      bfr[nt][kk] = *reinterpret_cast<const sh8*>(
          w1t + (size_t)(n0 + nt * 16 + l15) * KDIM + kk * 32 + lg * 8);

  const float b1v0 = b1[n0 + l15],      b1v1 = b1[n0 + 16 + l15];
  const float w2v0 = w2[n0 + l15],      w2v1 = w2[n0 + 16 + l15];
  const float b2v  = b2[0];

  const int b2b = (l15 >> 2) & 1;
  const int Eb  = l15 * 512 + 64 * b2b + ((lg * 16) ^ ((l15 & 3) << 4));
  const int Ob  = Eb - 128 * b2b;

  int ia0 = eip0[0],      ia1 = eip1[0];
  __builtin_amdgcn_sched_barrier(0);
  int ib0 = eip0[TM],     ib1 = eip1[TM];
  __builtin_amdgcn_sched_barrier(0);
  glds16(zb + (size_t)ia0 * IN_CH_C + (off0 >> 1), lds + 0 * 16384 + (2 * w + 0) * 1024);
  glds16(zb + (size_t)ia1 * IN_CH_C + (off1 >> 1), lds + 0 * 16384 + (2 * w + 1) * 1024);
  __builtin_amdgcn_sched_barrier(0);
  int jc0 = eip0[2 * TM], jc1 = eip1[2 * TM];
  __builtin_amdgcn_sched_barrier(0);
  glds16(zb + (size_t)ib0 * IN_CH_C + (off0 >> 1), lds + 1 * 16384 + (2 * w + 0) * 1024);
  glds16(zb + (size_t)ib1 * IN_CH_C + (off1 >> 1), lds + 1 * 16384 + (2 * w + 1) * 1024);
  __builtin_amdgcn_sched_barrier(0);

  int cur = 0, nx1 = 16384, nx2 = 32768;

#pragma unroll 1
  for (int t = 0; t < ntb; ++t) {
    __builtin_amdgcn_sched_barrier(0);
    asm volatile("s_waitcnt vmcnt(4) lgkmcnt(0)" ::: "memory");
    __builtin_amdgcn_s_barrier();
    __builtin_amdgcn_sched_barrier(0);

    const int tn = (t + 3 < ntb) ? (t + 3) : (ntb - 1);
    int ni0 = eip0[tn * TM];
    int ni1 = eip1[tn * TM];
    __builtin_amdgcn_sched_barrier(0);

    glds16(zb + (size_t)jc0 * IN_CH_C + (off0 >> 1), lds + nx2 + (2 * w + 0) * 1024);
    glds16(zb + (size_t)jc1 * IN_CH_C + (off1 >> 1), lds + nx2 + (2 * w + 1) * 1024);
    __builtin_amdgcn_sched_barrier(0);

    const f32x4 fz = {0.f, 0.f, 0.f, 0.f};
    f32x4 acc[2][2] = {{fz, fz}, {fz, fz}};
    __builtin_amdgcn_s_setprio(1);
#pragma unroll
    for (int kk = 0; kk < 8; ++kk) {
      const int kb_ = ((kk & 1) ? Ob : Eb) + kk * 64;
#pragma unroll
      for (int mt = 0; mt < 2; ++mt) {
        const sh8 af = *reinterpret_cast<const sh8*>(lds + cur + kb_ + mt * 8192);
        acc[mt][0] = __builtin_amdgcn_mfma_f32_16x16x32_bf16(af, bfr[0][kk], acc[mt][0], 0, 0, 0);
        acc[mt][1] = __builtin_amdgcn_mfma_f32_16x16x32_bf16(af, bfr[1][kk], acc[mt][1], 0, 0, 0);
      }
    }
    __builtin_amdgcn_s_setprio(0);

    float pl[2][4];
#pragma unroll
    for (int mt = 0; mt < 2; ++mt)
#pragma unroll
      for (int r = 0; r < 4; ++r) {
        float v0 = fmaxf(acc[mt][0][r] + b1v0, 0.f);
        float v1 = fmaxf(acc[mt][1][r] + b1v1, 0.f);
        pl[mt][r] = v0 * w2v0 + v1 * w2v1;
      }
#pragma unroll
    for (int s = 1; s < 16; s <<= 1)
#pragma unroll
      for (int mt = 0; mt < 2; ++mt)
#pragma unroll
        for (int r = 0; r < 4; ++r)
          pl[mt][r] += __shfl_xor(pl[mt][r], s, 64);
    if (l15 == 0) {
#pragma unroll
      for (int mt = 0; mt < 2; ++mt) {
        float4 v = make_float4(pl[mt][0], pl[mt][1], pl[mt][2], pl[mt][3]);
        *reinterpret_cast<float4*>(&red[(t & 1) * 256 + w * 32 + mt * 16 + lg * 4]) = v;
      }
    }

    if (t > 0 && tid < TM) {
      float s = b2v;
#pragma unroll
      for (int ww = 0; ww < 8; ++ww)
        s += red[((t - 1) & 1) * 256 + ww * 32 + tid];
      out[tb + (t - 1) * TM + tid] = 1.f / (1.f + __expf(-s));
    }

    jc0 = ni0; jc1 = ni1;
    int tmp = cur; cur = nx1; nx1 = nx2; nx2 = tmp;
  }

  __builtin_amdgcn_sched_barrier(0);
  asm volatile("s_waitcnt lgkmcnt(0)" ::: "memory");
  __builtin_amdgcn_s_barrier();
  __builtin_amdgcn_sched_barrier(0);
  if (tid < TM) {
    float s = b2v;
#pragma unroll
    for (int ww = 0; ww < 8; ++ww)
      s += red[((ntb - 1) & 1) * 256 + ww * 32 + tid];
    out[tb + (ntb - 1) * TM + tid] = 1.f / (1.f + __expf(-s));
  }
  asm volatile("s_waitcnt vmcnt(0)" ::: "memory");
}

// ============================ FALLBACK PATH ============================
#define BM 64
__global__ __launch_bounds__(512, 6) void decoder_fb(
    const float* __restrict__ z, const int* __restrict__ ei,
    const unsigned short* __restrict__ w1t, const float* __restrict__ b1,
    const float* __restrict__ w2, const float* __restrict__ b2,
    float* __restrict__ out)
{
  __shared__ __align__(16) unsigned char lds[BM * 512];
  const int tid = threadIdx.x, wave = tid >> 6, lane = tid & 63;
  const int l15 = lane & 15, lg = lane >> 4, base = blockIdx.x * BM;
  {
    const int e = tid & 63, w8 = tid >> 6, nd = w8 >> 2;
    const int idx = ei[nd * N_EDGES_C + base + e];
    const int swzw = (e & 7) << 4;
    char* dstrow = (char*)lds + e * 512;
    const float* src = z + (size_t)idx * IN_CH_C + (w8 & 3) * 32;
    float4 tf[8];
#pragma unroll
    for (int i = 0; i < 8; ++i) tf[i] = reinterpret_cast<const float4*>(src)[i];
#pragma unroll
    for (int i = 0; i < 4; ++i) {
      sh8 o; const float4 x0 = tf[2*i], x1 = tf[2*i+1];
      o[0]=(short)f2bf(x0.x); o[1]=(short)f2bf(x0.y); o[2]=(short)f2bf(x0.z); o[3]=(short)f2bf(x0.w);
      o[4]=(short)f2bf(x1.x); o[5]=(short)f2bf(x1.y); o[6]=(short)f2bf(x1.z); o[7]=(short)f2bf(x1.w);
      *reinterpret_cast<sh8*>(dstrow + ((w8 * 64 + i * 16) ^ swzw)) = o;
    }
  }
  __syncthreads();
  const int n0 = wave * 32;
  const int swz = (l15 & 7) << 4;
  const int Ebase = l15 * 512 + ((lg * 16) ^ swz);
  const int Obase = Ebase - ((swz & 64) << 1);
  const f32x4 fz = {0.f,0.f,0.f,0.f};
  f32x4 acc[4][2];
#pragma unroll
  for (int mt = 0; mt < 4; ++mt) { acc[mt][0] = fz; acc[mt][1] = fz; }
#pragma unroll
  for (int kk = 0; kk < 8; ++kk) {
    const int kOff = kk * 32 + lg * 8;
    sh8 bfrag[2];
#pragma unroll
    for (int nt = 0; nt < 2; ++nt)
      bfrag[nt] = *reinterpret_cast<const sh8*>(w1t + (size_t)(n0 + nt*16 + l15) * KDIM + kOff);
    const int kbase = ((kk & 1) ? Obase : Ebase) + kk * 64;
#pragma unroll
    for (int mt = 0; mt < 4; ++mt) {
      const sh8 af = *reinterpret_cast<const sh8*>((char*)lds + (kbase + mt * 8192));
      acc[mt][0] = __builtin_amdgcn_mfma_f32_16x16x32_bf16(af, bfrag[0], acc[mt][0], 0, 0, 0);
      acc[mt][1] = __builtin_amdgcn_mfma_f32_16x16x32_bf16(af, bfrag[1], acc[mt][1], 0, 0, 0);
    }
  }
  float plog[4][4];
#pragma unroll
  for (int mt = 0; mt < 4; ++mt)
#pragma unroll
    for (int r = 0; r < 4; ++r) plog[mt][r] = 0.f;
#pragma unroll
  for (int nt = 0; nt < 2; ++nt) {
    const int j = n0 + nt * 16 + l15;
    const float b1v = b1[j], w2v = w2[j];
#pragma unroll
    for (int mt = 0; mt < 4; ++mt)
#pragma unroll
      for (int r = 0; r < 4; ++r)
        plog[mt][r] = fmaf(fmaxf(acc[mt][nt][r] + b1v, 0.f), w2v, plog[mt][r]);
  }
#pragma unroll
  for (int s = 1; s < 16; s <<= 1)
#pragma unroll
    for (int mt = 0; mt < 4; ++mt)
#pragma unroll
      for (int r = 0; r < 4; ++r)
        plog[mt][r] += __shfl_xor(plog[mt][r], s, 64);
  __syncthreads();
  float* red = (float*)lds;
  if (l15 == 0)
#pragma unroll
    for (int mt = 0; mt < 4; ++mt)
#pragma unroll
      for (int r = 0; r < 4; ++r)
        red[wave * 64 + mt * 16 + lg * 4 + r] = plog[mt][r];
  __syncthreads();
  if (tid < BM) {
    float s = b2[0];
#pragma unroll
    for (int w = 0; w < 8; ++w) s += red[w * 64 + tid];
    out[base + tid] = 1.f / (1.f + __expf(-s));
  }
}

extern "C" void kernel_launch(void* const* d_in, const int* in_sizes, int n_in,
                              void* d_out, int out_size, void* d_ws, size_t ws_size,
                              hipStream_t stream) {
  const float* z  = (const float*)d_in[0];
  const int*   ei = (const int*)d_in[1];
  const float* W1 = (const float*)d_in[2];
  const float* b1 = (const float*)d_in[3];
  const float* W2 = (const float*)d_in[4];
  const float* b2 = (const float*)d_in[5];
  float* out = (float*)d_out;

  const size_t o_w1   = 0;                                   // 128 KB
  const size_t o_zw   = 131072;
  const size_t need_A = o_zw + (size_t)N_NODES_C * 512 * 2;  // 51,331,072
  const size_t need_mid = 131072 + (size_t)N_NODES_C * IN_CH_C * 2; // 12,931,072

  if (ws_size >= need_A) {
    unsigned short* w1ct = (unsigned short*)((char*)d_ws + o_w1);
    unsigned short* zw   = (unsigned short*)((char*)d_ws + o_zw);
    cvt_w1ct_kernel<<<128, 512, 0, stream>>>(W1, w1ct);
    build_zw_kernel<<<(N_NODES_C + 63) / 64, 512, 0, stream>>>(z, w1ct, b1, zw);
    edge_pass_pipe3<<<3125, 256, 0, stream>>>(zw, ei, W2, b2, out);
  } else if (ws_size >= need_mid) {
    unsigned short* w1t = (unsigned short*)d_ws;
    unsigned short* zb  = (unsigned short*)((char*)d_ws + 131072);
    cvt_w1t_kernel<<<KDIM, HIDDEN_C, 0, stream>>>(W1, w1t);
    cvt_z_kernel<<<(N_NODES_C * IN_CH_C / 4) / 256, 256, 0, stream>>>(z, zb);
    decoder_persist<<<NBLK, THREADS, 0, stream>>>(zb, ei, w1t, b1, W2, b2, out);
  } else {
    unsigned short* w1t = (unsigned short*)d_ws;
    cvt_w1t_kernel<<<KDIM, HIDDEN_C, 0, stream>>>(W1, w1t);
    decoder_fb<<<N_EDGES_C / BM, 512, 0, stream>>>(z, ei, w1t, b1, W2, b2, out);
  }
}